// Round 10
// baseline (199.422 us; speedup 1.0000x reference)
//
#include <hip/hip_runtime.h>
#include <hip/hip_bf16.h>

#define HWs 25600   // 160*160
#define NB 16       // batches
#define NC 128      // channels
#define NS 256      // selected per batch
#define NN 4096     // NB*NS total rows

typedef __attribute__((ext_vector_type(8))) short bf16x8;
typedef __attribute__((ext_vector_type(4))) float f32x4;
typedef __attribute__((ext_vector_type(4))) int i32x4;
typedef unsigned long long u64;

// ==================== K0: exact top-256 per batch (verified r3 LDS-radix) ====================
__global__ __launch_bounds__(256) void topk_kernel(const float* __restrict__ score,
                                                   int* __restrict__ sel) {
  __shared__ unsigned int vals[HWs];          // 100 KB (pure kernel, occupancy irrelevant)
  __shared__ int hist[256];
  __shared__ int scan_s[256];
  __shared__ int scan_eq[256];
  __shared__ int bc_dig, bc_k;
  int b = blockIdx.x;
  int tid = threadIdx.x;
  const float* sc = score + (size_t)b * HWs;
  for (int i = tid; i < HWs; i += 256) vals[i] = __float_as_uint(sc[i]);
  __syncthreads();
  unsigned prefix = 0; int k = NS;
  for (int d = 3; d >= 0; --d) {
    int sh = d * 8;
    hist[tid] = 0; __syncthreads();
    unsigned maskHigh = (d == 3) ? 0u : (0xFFFFFFFFu << (sh + 8));
    for (int i = tid; i < HWs; i += 256) {
      unsigned v = vals[i];
      if ((v & maskHigh) == prefix) atomicAdd(&hist[(v >> sh) & 255], 1);
    }
    __syncthreads();
    int v = hist[255 - tid];
    scan_s[tid] = v; __syncthreads();
    for (int off = 1; off < 256; off <<= 1) {
      int a = (tid >= off) ? scan_s[tid - off] : 0;
      __syncthreads();
      scan_s[tid] += a; __syncthreads();
    }
    int q = 255 - tid;
    int Sq = scan_s[tid];          // count with digit >= q under prefix
    int before = Sq - hist[q];     // count with digit > q
    if (before < k && k <= Sq) { bc_dig = q; bc_k = k - before; }
    __syncthreads();
    prefix |= ((unsigned)bc_dig) << sh;
    k = bc_k;
    __syncthreads();
  }
  unsigned t = prefix;
  int cstart = tid * 100, cend = cstart + 100;
  int cgt = 0, ceq = 0;
  for (int i = cstart; i < cend; ++i) {
    unsigned v = vals[i];
    cgt += (v > t) ? 1 : 0;
    ceq += (v == t) ? 1 : 0;
  }
  scan_s[tid] = cgt; scan_eq[tid] = ceq; __syncthreads();
  for (int off = 1; off < 256; off <<= 1) {
    int ag = (tid >= off) ? scan_s[tid - off] : 0;
    int ae = (tid >= off) ? scan_eq[tid - off] : 0;
    __syncthreads();
    scan_s[tid] += ag; scan_eq[tid] += ae; __syncthreads();
  }
  int total_gt = scan_s[255];
  int need = NS - total_gt;
  int g = scan_s[tid] - cgt;
  int e = scan_eq[tid] - ceq;
  for (int i = cstart; i < cend; ++i) {
    unsigned v = vals[i];
    if (v > t) { sel[b * NS + g] = i; ++g; }
    else if (v == t) { if (e < need) sel[b * NS + total_gt + e] = i; ++e; }
  }
}

// ==================== K2: gather+norm (1024 blocks) + zero deg (verified r8) ====================
__global__ __launch_bounds__(256) void k2_kernel(const float* __restrict__ z,
                                                 const int* __restrict__ sel,
                                                 float* __restrict__ feats,
                                                 ushort* __restrict__ nfb,
                                                 int* __restrict__ deg) {
  const int tid = threadIdx.x;
  const int bid = blockIdx.x;
  if (bid < 4) {   // zero deg[4096] (accumulated by k3's atomicAdd next kernel)
    *(i32x4*)&deg[bid * 1024 + tid * 4] = (i32x4){0, 0, 0, 0};
  }
  int row = bid * 4 + (tid >> 6);
  int lane = tid & 63;
  int b = row >> 8;
  int idx = sel[row];
  const float* zb = z + (size_t)b * NC * HWs + idx;
  float v0 = zb[(size_t)lane * HWs];
  float v1 = zb[(size_t)(lane + 64) * HWs];
  float ss = v0 * v0 + v1 * v1;
  #pragma unroll
  for (int off = 32; off; off >>= 1) ss += __shfl_xor(ss, off);
  float denom = fmaxf(sqrtf(ss), 1e-12f);
  feats[row * NC + lane] = v0;
  feats[row * NC + lane + 64] = v1;
  __hip_bfloat16 h0 = __float2bfloat16(v0 / denom);
  __hip_bfloat16 h1 = __float2bfloat16(v1 / denom);
  nfb[row * NC + lane] = *reinterpret_cast<ushort*>(&h0);
  nfb[row * NC + lane + 64] = *reinterpret_cast<ushort*>(&h1);
}

// ==================== K3: sim MFMA (4096 tiles) + fused deg (verified r8) ====================
__global__ __launch_bounds__(256) void k3_kernel(const ushort* __restrict__ nfb,
                                                 u64* __restrict__ adj,
                                                 int* __restrict__ deg) {
  __shared__ __align__(16) ushort tA[64 * 128];
  __shared__ __align__(16) ushort tB[64 * 128];
  __shared__ u64 rowbits[64];
  const int tid = threadIdx.x;
  const int bid = blockIdx.x;
  int I0 = (bid & 63) * 64, J0 = (bid >> 6) * 64;
  if (tid < 64) rowbits[tid] = 0ull;
  for (int f = tid; f < 1024; f += 256) {
    int r = f >> 4, c = f & 15;
    int scnk = c ^ (r & 7);
    *(i32x4*)&tA[r * 128 + scnk * 8] = *(const i32x4*)(nfb + (size_t)(I0 + r) * NC + c * 8);
    *(i32x4*)&tB[r * 128 + scnk * 8] = *(const i32x4*)(nfb + (size_t)(J0 + r) * NC + c * 8);
  }
  __syncthreads();
  int w = tid >> 6, l = tid & 63;
  int r = l & 15, kg = l >> 4;
  f32x4 acc[4] = {{0.f, 0.f, 0.f, 0.f}, {0.f, 0.f, 0.f, 0.f},
                  {0.f, 0.f, 0.f, 0.f}, {0.f, 0.f, 0.f, 0.f}};
  int Ar = 16 * w + r;
  #pragma unroll
  for (int kk = 0; kk < 4; ++kk) {
    int chunkA = (kk * 4 + kg) ^ (Ar & 7);
    bf16x8 a = *(bf16x8*)&tA[Ar * 128 + chunkA * 8];
    #pragma unroll
    for (int j = 0; j < 4; ++j) {
      int Bc = 16 * j + r;
      int chunkB = (kk * 4 + kg) ^ (Bc & 7);
      bf16x8 bf = *(bf16x8*)&tB[Bc * 128 + chunkB * 8];
      acc[j] = __builtin_amdgcn_mfma_f32_16x16x32_bf16(a, bf, acc[j], 0, 0, 0);
    }
  }
  #pragma unroll
  for (int q = 0; q < 4; ++q) {
    u64 m = 0ull;
    #pragma unroll
    for (int j = 0; j < 4; ++j) {
      float simv = acc[j][q];
      if ((1.0f - simv) * 0.5f < 0.2f) m |= 1ull << (16 * j + (l & 15));
    }
    if (m) atomicOr(&rowbits[16 * w + (l >> 4) * 4 + q], m);
  }
  __syncthreads();
  if (tid < 64) {
    u64 rb = rowbits[tid];
    adj[(size_t)(I0 + tid) * 64 + (bid >> 6)] = rb;
    atomicAdd(&deg[I0 + tid], __popcll(rb));   // int sum, deterministic
  }
}

// ==================== K4: agg (deg-based) + GEMM(+bias) + scatter (verified r8) ====================
__global__ __launch_bounds__(256) void k4_kernel(const u64* __restrict__ adj,
                                                 const float* __restrict__ feats,
                                                 const int* __restrict__ deg,
                                                 const float* __restrict__ Wg,
                                                 const float* __restrict__ bg,
                                                 const int* __restrict__ sel,
                                                 float* __restrict__ out) {
  __shared__ __align__(16) float Wt[NC * 132];    // W transposed [cp][c]
  __shared__ __align__(16) float aggT[16 * 132];
  int tid = threadIdx.x;
  int r0 = blockIdx.x * 16;
  for (int f = tid; f < NC * NC; f += 256) {
    int c = f >> 7, cp = f & 127;
    Wt[cp * 132 + c] = Wg[f];
  }
  int w = tid >> 6, lane = tid & 63;
  for (int rr = 0; rr < 4; ++rr) {
    int lrow = w * 4 + rr;
    int row = r0 + lrow;
    u64 mw = adj[(size_t)row * 64 + lane];
    float dinv_i = 1.0f / sqrtf(fmaxf((float)deg[row], 1.0f));
    float acc0 = 0.f, acc1 = 0.f;
    for (int wi = 0; wi < 64; ++wi) {
      u64 w64 = __shfl((long long)mw, wi);
      while (w64) {
        int bit = __builtin_ctzll(w64);
        w64 &= w64 - 1;
        int j = wi * 64 + bit;            // ascending j (deterministic order)
        float dj = 1.0f / sqrtf(fmaxf((float)deg[j], 1.0f));
        acc0 += dj * feats[(size_t)j * NC + lane];
        acc1 += dj * feats[(size_t)j * NC + lane + 64];
      }
    }
    aggT[lrow * 132 + lane] = dinv_i * acc0;
    aggT[lrow * 132 + lane + 64] = dinv_i * acc1;
  }
  __syncthreads();
  int cp = tid & 127;
  int rsub = tid >> 7;
  float acc[8];
  float bb = bg[cp];
  #pragma unroll
  for (int q = 0; q < 8; ++q) acc[q] = bb;
  for (int c4 = 0; c4 < 32; ++c4) {
    float4 w4 = *(const float4*)&Wt[cp * 132 + c4 * 4];
    #pragma unroll
    for (int q = 0; q < 8; ++q) {
      float4 a4 = *(const float4*)&aggT[(rsub + 2 * q) * 132 + c4 * 4];
      acc[q] += a4.x * w4.x + a4.y * w4.y + a4.z * w4.z + a4.w * w4.w;
    }
  }
  #pragma unroll
  for (int q = 0; q < 8; ++q) {
    int row = r0 + rsub + 2 * q;
    int batch = row >> 8;
    int idx = sel[row];
    out[(size_t)(batch * NC + cp) * HWs + idx] = acc[q];
  }
}

extern "C" void kernel_launch(void* const* d_in, const int* in_sizes, int n_in,
                              void* d_out, int out_size, void* d_ws, size_t ws_size,
                              hipStream_t stream) {
  const float* z     = (const float*)d_in[0];
  const float* score = (const float*)d_in[1];
  const float* Wg    = (const float*)d_in[2];
  const float* bg    = (const float*)d_in[3];
  float* out = (float*)d_out;

  char* ws = (char*)d_ws;
  size_t off = 0;
  auto alloc = [&](size_t bytes) {
    void* p = ws + off;
    off = (off + bytes + 255) & ~(size_t)255;
    return p;
  };
  int* sel     = (int*)alloc(NN * sizeof(int));
  float* feats = (float*)alloc((size_t)NN * NC * sizeof(float));
  ushort* nfb  = (ushort*)alloc((size_t)NN * NC * sizeof(ushort));
  u64* adj     = (u64*)alloc((size_t)NN * 64 * sizeof(u64));
  int* deg     = (int*)alloc(NN * sizeof(int));

  // Bulk copy z -> out via the runtime's optimized D2D path (SDMA/blit).
  hipMemcpyAsync(out, z, (size_t)NB * NC * HWs * sizeof(float),
                 hipMemcpyDeviceToDevice, stream);
  topk_kernel<<<NB, 256, 0, stream>>>(score, sel);
  k2_kernel<<<NN / 4, 256, 0, stream>>>(z, sel, feats, nfb, deg);
  k3_kernel<<<4096, 256, 0, stream>>>(nfb, adj, deg);
  k4_kernel<<<256, 256, 0, stream>>>(adj, feats, deg, Wg, bg, sel, out);
}

// Round 11
// 159.874 us; speedup vs baseline: 1.2474x; 1.2474x over previous
//
#include <hip/hip_runtime.h>
#include <hip/hip_bf16.h>

#define HWs 25600   // 160*160
#define NB 16       // batches
#define NC 128      // channels
#define NS 256      // selected per batch
#define NN 4096     // NB*NS total rows
#define N4 13107200 // NB*NC*HWs/4 float4 elements of z
#define CP_U 8
#define K1_CPB 6400 // 6400 blocks x 8 chunks x 256 thr = 13107200 f4 = 100% of z

typedef __attribute__((ext_vector_type(8))) short bf16x8;
typedef __attribute__((ext_vector_type(4))) float f32x4;
typedef __attribute__((ext_vector_type(4))) int i32x4;
typedef unsigned long long u64;

// Forced-ILP block copy. NT *loads* (z doesn't allocate in L3 -> L3 dedicated
// to the out write stream); plain cached stores (correctness proven in r8).
template <int U>
__device__ __forceinline__ void copy_slice(const float4* __restrict__ zz,
                                           float4* __restrict__ oo,
                                           int cb, int tid) {
  size_t start = (size_t)cb * (U * 256) + tid;
  f32x4 v[U];
  #pragma unroll
  for (int k = 0; k < U; ++k)
    v[k] = __builtin_nontemporal_load((const f32x4*)&zz[start + k * 256]);
  __builtin_amdgcn_sched_barrier(0);
  #pragma unroll
  for (int k = 0; k < U; ++k)
    *(f32x4*)&oo[start + k * 256] = v[k];
}

// ==================== K1: topk (score from L2, ~3KB LDS) | copy 100% ====================
__global__ __launch_bounds__(256) void k1_kernel(const float* __restrict__ z,
                                                 const float* __restrict__ score,
                                                 float* __restrict__ out,
                                                 int* __restrict__ sel) {
  __shared__ int hist[256];
  __shared__ int scan_s[256];
  __shared__ int scan_eq[256];
  __shared__ int bc_dig, bc_k;
  const int tid = threadIdx.x;
  const int bid = blockIdx.x;

  if (bid >= NB) {
    copy_slice<CP_U>((const float4*)z, (float4*)out, bid - NB, tid);
    return;
  }

  int b = bid;
  const float* sc = score + (size_t)b * HWs;
  const float4* sc4 = (const float4*)sc;

  // ---- radix select: 4 passes of 8-bit digits, score re-read from L2 ----
  unsigned prefix = 0; int k = NS;
  for (int d = 3; d >= 0; --d) {
    int sh = d * 8;
    hist[tid] = 0; __syncthreads();
    unsigned maskHigh = (d == 3) ? 0u : (0xFFFFFFFFu << (sh + 8));
    #pragma unroll 5
    for (int i4 = 0; i4 < 25; ++i4) {       // thread covers f4 range [tid*25, tid*25+25)
      float4 f = sc4[tid * 25 + i4];
      const float* fp = (const float*)&f;
      #pragma unroll
      for (int c = 0; c < 4; ++c) {
        unsigned v = __float_as_uint(fp[c]);
        if ((v & maskHigh) == prefix) atomicAdd(&hist[(v >> sh) & 255], 1);
      }
    }
    __syncthreads();
    int val = hist[255 - tid];
    scan_s[tid] = val; __syncthreads();
    for (int off = 1; off < 256; off <<= 1) {
      int a = (tid >= off) ? scan_s[tid - off] : 0;
      __syncthreads();
      scan_s[tid] += a; __syncthreads();
    }
    int q = 255 - tid;
    int Sq = scan_s[tid];          // count with digit >= q under prefix
    int before = Sq - hist[q];     // count with digit > q
    if (before < k && k <= Sq) { bc_dig = q; bc_k = k - before; }
    __syncthreads();
    prefix |= ((unsigned)bc_dig) << sh;
    k = bc_k;
    __syncthreads();
  }
  unsigned t = prefix;

  // ---- stable compaction: all v > t, plus first (NS-#gt) v == t by index ----
  int cgt = 0, ceq = 0;
  #pragma unroll 5
  for (int i4 = 0; i4 < 25; ++i4) {
    float4 f = sc4[tid * 25 + i4];
    const float* fp = (const float*)&f;
    #pragma unroll
    for (int c = 0; c < 4; ++c) {
      unsigned v = __float_as_uint(fp[c]);
      cgt += (v > t) ? 1 : 0;
      ceq += (v == t) ? 1 : 0;
    }
  }
  scan_s[tid] = cgt; scan_eq[tid] = ceq; __syncthreads();
  for (int off = 1; off < 256; off <<= 1) {
    int ag = (tid >= off) ? scan_s[tid - off] : 0;
    int ae = (tid >= off) ? scan_eq[tid - off] : 0;
    __syncthreads();
    scan_s[tid] += ag; scan_eq[tid] += ae; __syncthreads();
  }
  int total_gt = scan_s[255];
  int need = NS - total_gt;
  int g = scan_s[tid] - cgt;
  int e = scan_eq[tid] - ceq;
  for (int i4 = 0; i4 < 25; ++i4) {        // in-order within thread -> ascending index
    float4 f = sc4[tid * 25 + i4];
    const float* fp = (const float*)&f;
    #pragma unroll
    for (int c = 0; c < 4; ++c) {
      int i = tid * 100 + i4 * 4 + c;
      unsigned v = __float_as_uint(fp[c]);
      if (v > t) { sel[b * NS + g] = i; ++g; }
      else if (v == t) { if (e < need) sel[b * NS + total_gt + e] = i; ++e; }
    }
  }
}

// ==================== K2: gather+norm (1024 blocks, pure) + zero deg ====================
__global__ __launch_bounds__(256) void k2_kernel(const float* __restrict__ z,
                                                 const int* __restrict__ sel,
                                                 float* __restrict__ feats,
                                                 ushort* __restrict__ nfb,
                                                 int* __restrict__ deg) {
  const int tid = threadIdx.x;
  const int bid = blockIdx.x;
  if (bid < 4) {   // zero deg[4096] (accumulated by k3's atomicAdd next kernel)
    *(i32x4*)&deg[bid * 1024 + tid * 4] = (i32x4){0, 0, 0, 0};
  }
  int row = bid * 4 + (tid >> 6);
  int lane = tid & 63;
  int b = row >> 8;
  int idx = sel[row];
  const float* zb = z + (size_t)b * NC * HWs + idx;
  float v0 = zb[(size_t)lane * HWs];
  float v1 = zb[(size_t)(lane + 64) * HWs];
  float ss = v0 * v0 + v1 * v1;
  #pragma unroll
  for (int off = 32; off; off >>= 1) ss += __shfl_xor(ss, off);
  float denom = fmaxf(sqrtf(ss), 1e-12f);
  feats[row * NC + lane] = v0;
  feats[row * NC + lane + 64] = v1;
  __hip_bfloat16 h0 = __float2bfloat16(v0 / denom);
  __hip_bfloat16 h1 = __float2bfloat16(v1 / denom);
  nfb[row * NC + lane] = *reinterpret_cast<ushort*>(&h0);
  nfb[row * NC + lane + 64] = *reinterpret_cast<ushort*>(&h1);
}

// ==================== K3: sim MFMA (4096 tiles, pure) + fused deg ====================
__global__ __launch_bounds__(256) void k3_kernel(const ushort* __restrict__ nfb,
                                                 u64* __restrict__ adj,
                                                 int* __restrict__ deg) {
  __shared__ __align__(16) ushort tA[64 * 128];
  __shared__ __align__(16) ushort tB[64 * 128];
  __shared__ u64 rowbits[64];
  const int tid = threadIdx.x;
  const int bid = blockIdx.x;
  int I0 = (bid & 63) * 64, J0 = (bid >> 6) * 64;
  if (tid < 64) rowbits[tid] = 0ull;
  for (int f = tid; f < 1024; f += 256) {
    int r = f >> 4, c = f & 15;
    int scnk = c ^ (r & 7);
    *(i32x4*)&tA[r * 128 + scnk * 8] = *(const i32x4*)(nfb + (size_t)(I0 + r) * NC + c * 8);
    *(i32x4*)&tB[r * 128 + scnk * 8] = *(const i32x4*)(nfb + (size_t)(J0 + r) * NC + c * 8);
  }
  __syncthreads();
  int w = tid >> 6, l = tid & 63;
  int r = l & 15, kg = l >> 4;
  f32x4 acc[4] = {{0.f, 0.f, 0.f, 0.f}, {0.f, 0.f, 0.f, 0.f},
                  {0.f, 0.f, 0.f, 0.f}, {0.f, 0.f, 0.f, 0.f}};
  int Ar = 16 * w + r;
  #pragma unroll
  for (int kk = 0; kk < 4; ++kk) {
    int chunkA = (kk * 4 + kg) ^ (Ar & 7);
    bf16x8 a = *(bf16x8*)&tA[Ar * 128 + chunkA * 8];
    #pragma unroll
    for (int j = 0; j < 4; ++j) {
      int Bc = 16 * j + r;
      int chunkB = (kk * 4 + kg) ^ (Bc & 7);
      bf16x8 bf = *(bf16x8*)&tB[Bc * 128 + chunkB * 8];
      acc[j] = __builtin_amdgcn_mfma_f32_16x16x32_bf16(a, bf, acc[j], 0, 0, 0);
    }
  }
  #pragma unroll
  for (int q = 0; q < 4; ++q) {
    u64 m = 0ull;
    #pragma unroll
    for (int j = 0; j < 4; ++j) {
      float simv = acc[j][q];
      if ((1.0f - simv) * 0.5f < 0.2f) m |= 1ull << (16 * j + (l & 15));
    }
    if (m) atomicOr(&rowbits[16 * w + (l >> 4) * 4 + q], m);
  }
  __syncthreads();
  if (tid < 64) {
    u64 rb = rowbits[tid];
    adj[(size_t)(I0 + tid) * 64 + (bid >> 6)] = rb;
    atomicAdd(&deg[I0 + tid], __popcll(rb));   // int sum, deterministic
  }
}

// ==================== K4: agg (deg-based) + GEMM(+bias) + scatter ====================
__global__ __launch_bounds__(256) void k4_kernel(const u64* __restrict__ adj,
                                                 const float* __restrict__ feats,
                                                 const int* __restrict__ deg,
                                                 const float* __restrict__ Wg,
                                                 const float* __restrict__ bg,
                                                 const int* __restrict__ sel,
                                                 float* __restrict__ out) {
  __shared__ __align__(16) float Wt[NC * 132];    // W transposed [cp][c]
  __shared__ __align__(16) float aggT[16 * 132];
  int tid = threadIdx.x;
  int r0 = blockIdx.x * 16;
  for (int f = tid; f < NC * NC; f += 256) {
    int c = f >> 7, cp = f & 127;
    Wt[cp * 132 + c] = Wg[f];
  }
  int w = tid >> 6, lane = tid & 63;
  for (int rr = 0; rr < 4; ++rr) {
    int lrow = w * 4 + rr;
    int row = r0 + lrow;
    u64 mw = adj[(size_t)row * 64 + lane];
    float dinv_i = 1.0f / sqrtf(fmaxf((float)deg[row], 1.0f));
    float acc0 = 0.f, acc1 = 0.f;
    for (int wi = 0; wi < 64; ++wi) {
      u64 w64 = __shfl((long long)mw, wi);
      while (w64) {
        int bit = __builtin_ctzll(w64);
        w64 &= w64 - 1;
        int j = wi * 64 + bit;            // ascending j (deterministic order)
        float dj = 1.0f / sqrtf(fmaxf((float)deg[j], 1.0f));
        acc0 += dj * feats[(size_t)j * NC + lane];
        acc1 += dj * feats[(size_t)j * NC + lane + 64];
      }
    }
    aggT[lrow * 132 + lane] = dinv_i * acc0;
    aggT[lrow * 132 + lane + 64] = dinv_i * acc1;
  }
  __syncthreads();
  int cp = tid & 127;
  int rsub = tid >> 7;
  float acc[8];
  float bb = bg[cp];
  #pragma unroll
  for (int q = 0; q < 8; ++q) acc[q] = bb;
  for (int c4 = 0; c4 < 32; ++c4) {
    float4 w4 = *(const float4*)&Wt[cp * 132 + c4 * 4];
    #pragma unroll
    for (int q = 0; q < 8; ++q) {
      float4 a4 = *(const float4*)&aggT[(rsub + 2 * q) * 132 + c4 * 4];
      acc[q] += a4.x * w4.x + a4.y * w4.y + a4.z * w4.z + a4.w * w4.w;
    }
  }
  #pragma unroll
  for (int q = 0; q < 8; ++q) {
    int row = r0 + rsub + 2 * q;
    int batch = row >> 8;
    int idx = sel[row];
    out[(size_t)(batch * NC + cp) * HWs + idx] = acc[q];
  }
}

extern "C" void kernel_launch(void* const* d_in, const int* in_sizes, int n_in,
                              void* d_out, int out_size, void* d_ws, size_t ws_size,
                              hipStream_t stream) {
  const float* z     = (const float*)d_in[0];
  const float* score = (const float*)d_in[1];
  const float* Wg    = (const float*)d_in[2];
  const float* bg    = (const float*)d_in[3];
  float* out = (float*)d_out;

  char* ws = (char*)d_ws;
  size_t off = 0;
  auto alloc = [&](size_t bytes) {
    void* p = ws + off;
    off = (off + bytes + 255) & ~(size_t)255;
    return p;
  };
  int* sel     = (int*)alloc(NN * sizeof(int));
  float* feats = (float*)alloc((size_t)NN * NC * sizeof(float));
  ushort* nfb  = (ushort*)alloc((size_t)NN * NC * sizeof(ushort));
  u64* adj     = (u64*)alloc((size_t)NN * 64 * sizeof(u64));
  int* deg     = (int*)alloc(NN * sizeof(int));

  k1_kernel<<<NB + K1_CPB, 256, 0, stream>>>(z, score, out, sel);
  k2_kernel<<<NN / 4, 256, 0, stream>>>(z, sel, feats, nfb, deg);
  k3_kernel<<<4096, 256, 0, stream>>>(nfb, adj, deg);
  k4_kernel<<<256, 256, 0, stream>>>(adj, feats, deg, Wg, bg, sel, out);
}

// Round 12
// 144.442 us; speedup vs baseline: 1.3806x; 1.1068x over previous
//
#include <hip/hip_runtime.h>
#include <hip/hip_bf16.h>

#define HWs 25600   // 160*160
#define NB 16       // batches
#define NC 128      // channels
#define NS 256      // selected per batch
#define NN 4096     // NB*NS total rows
#define N4 13107200 // NB*NC*HWs/4 float4 elements of z
#define CP_U 10
#define K1_CPB 5120 // 5120 blocks x 10 chunks x 256 thr = 13107200 f4 = 100% of z

typedef __attribute__((ext_vector_type(8))) short bf16x8;
typedef __attribute__((ext_vector_type(4))) float f32x4;
typedef __attribute__((ext_vector_type(4))) int i32x4;
typedef unsigned long long u64;

// Deep-ILP block copy: U=10 explicit f32x4 temporaries (40 data VGPRs live
// across the barrier -> 10 loads in flight per wave), NT loads (r11).
template <int U>
__device__ __forceinline__ void copy_slice(const float4* __restrict__ zz,
                                           float4* __restrict__ oo,
                                           int cb, int tid) {
  size_t start = (size_t)cb * (U * 256) + tid;
  f32x4 v[U];
  #pragma unroll
  for (int k = 0; k < U; ++k)
    v[k] = __builtin_nontemporal_load((const f32x4*)&zz[start + k * 256]);
  __builtin_amdgcn_sched_barrier(0);
  #pragma unroll
  for (int k = 0; k < U; ++k)
    *(f32x4*)&oo[start + k * 256] = v[k];
}

// ==================== K1: topk (batch-5 pipelined reads) | copy 100% ====================
__global__ __launch_bounds__(256, 6) void k1_kernel(const float* __restrict__ z,
                                                    const float* __restrict__ score,
                                                    float* __restrict__ out,
                                                    int* __restrict__ sel) {
  __shared__ int hist[256];
  __shared__ int scan_s[256];
  __shared__ int scan_eq[256];
  __shared__ int bc_dig, bc_k;
  const int tid = threadIdx.x;
  const int bid = blockIdx.x;

  if (bid >= NB) {
    copy_slice<CP_U>((const float4*)z, (float4*)out, bid - NB, tid);
    return;
  }

  int b = bid;
  const float4* sc4 = (const float4*)(score + (size_t)b * HWs);

  // ---- radix select: 4 passes of 8-bit digits; reads pipelined 5-deep ----
  unsigned prefix = 0; int k = NS;
  for (int d = 3; d >= 0; --d) {
    int sh = d * 8;
    hist[tid] = 0; __syncthreads();
    unsigned maskHigh = (d == 3) ? 0u : (0xFFFFFFFFu << (sh + 8));
    #pragma unroll 1
    for (int g5 = 0; g5 < 5; ++g5) {       // 5 groups x 5 independent float4 loads
      float4 f[5];
      #pragma unroll
      for (int u = 0; u < 5; ++u) f[u] = sc4[tid * 25 + g5 * 5 + u];
      #pragma unroll
      for (int u = 0; u < 5; ++u) {
        const float* fp = (const float*)&f[u];
        #pragma unroll
        for (int c = 0; c < 4; ++c) {
          unsigned v = __float_as_uint(fp[c]);
          if ((v & maskHigh) == prefix) atomicAdd(&hist[(v >> sh) & 255], 1);
        }
      }
    }
    __syncthreads();
    int val = hist[255 - tid];
    scan_s[tid] = val; __syncthreads();
    for (int off = 1; off < 256; off <<= 1) {
      int a = (tid >= off) ? scan_s[tid - off] : 0;
      __syncthreads();
      scan_s[tid] += a; __syncthreads();
    }
    int q = 255 - tid;
    int Sq = scan_s[tid];          // count with digit >= q under prefix
    int before = Sq - hist[q];     // count with digit > q
    if (before < k && k <= Sq) { bc_dig = q; bc_k = k - before; }
    __syncthreads();
    prefix |= ((unsigned)bc_dig) << sh;
    k = bc_k;
    __syncthreads();
  }
  unsigned t = prefix;

  // ---- stable compaction: all v > t, plus first (NS-#gt) v == t by index ----
  int cgt = 0, ceq = 0;
  #pragma unroll 1
  for (int g5 = 0; g5 < 5; ++g5) {
    float4 f[5];
    #pragma unroll
    for (int u = 0; u < 5; ++u) f[u] = sc4[tid * 25 + g5 * 5 + u];
    #pragma unroll
    for (int u = 0; u < 5; ++u) {
      const float* fp = (const float*)&f[u];
      #pragma unroll
      for (int c = 0; c < 4; ++c) {
        unsigned v = __float_as_uint(fp[c]);
        cgt += (v > t) ? 1 : 0;
        ceq += (v == t) ? 1 : 0;
      }
    }
  }
  scan_s[tid] = cgt; scan_eq[tid] = ceq; __syncthreads();
  for (int off = 1; off < 256; off <<= 1) {
    int ag = (tid >= off) ? scan_s[tid - off] : 0;
    int ae = (tid >= off) ? scan_eq[tid - off] : 0;
    __syncthreads();
    scan_s[tid] += ag; scan_eq[tid] += ae; __syncthreads();
  }
  int total_gt = scan_s[255];
  int need = NS - total_gt;
  int g = scan_s[tid] - cgt;
  int e = scan_eq[tid] - ceq;
  #pragma unroll 1
  for (int g5 = 0; g5 < 5; ++g5) {         // ascending index order preserved
    float4 f[5];
    #pragma unroll
    for (int u = 0; u < 5; ++u) f[u] = sc4[tid * 25 + g5 * 5 + u];
    #pragma unroll
    for (int u = 0; u < 5; ++u) {
      const float* fp = (const float*)&f[u];
      #pragma unroll
      for (int c = 0; c < 4; ++c) {
        int i = tid * 100 + g5 * 20 + u * 4 + c;
        unsigned v = __float_as_uint(fp[c]);
        if (v > t) { sel[b * NS + g] = i; ++g; }
        else if (v == t) { if (e < need) sel[b * NS + total_gt + e] = i; ++e; }
      }
    }
  }
}

// ==================== K2: gather+norm (1024 blocks, pure) + zero deg ====================
__global__ __launch_bounds__(256) void k2_kernel(const float* __restrict__ z,
                                                 const int* __restrict__ sel,
                                                 float* __restrict__ feats,
                                                 ushort* __restrict__ nfb,
                                                 int* __restrict__ deg) {
  const int tid = threadIdx.x;
  const int bid = blockIdx.x;
  if (bid < 4) {   // zero deg[4096] (accumulated by k3's atomicAdd next kernel)
    *(i32x4*)&deg[bid * 1024 + tid * 4] = (i32x4){0, 0, 0, 0};
  }
  int row = bid * 4 + (tid >> 6);
  int lane = tid & 63;
  int b = row >> 8;
  int idx = sel[row];
  const float* zb = z + (size_t)b * NC * HWs + idx;
  float v0 = zb[(size_t)lane * HWs];
  float v1 = zb[(size_t)(lane + 64) * HWs];
  float ss = v0 * v0 + v1 * v1;
  #pragma unroll
  for (int off = 32; off; off >>= 1) ss += __shfl_xor(ss, off);
  float denom = fmaxf(sqrtf(ss), 1e-12f);
  feats[row * NC + lane] = v0;
  feats[row * NC + lane + 64] = v1;
  __hip_bfloat16 h0 = __float2bfloat16(v0 / denom);
  __hip_bfloat16 h1 = __float2bfloat16(v1 / denom);
  nfb[row * NC + lane] = *reinterpret_cast<ushort*>(&h0);
  nfb[row * NC + lane + 64] = *reinterpret_cast<ushort*>(&h1);
}

// ==================== K3: sim MFMA (4096 tiles, pure) + fused deg ====================
__global__ __launch_bounds__(256) void k3_kernel(const ushort* __restrict__ nfb,
                                                 u64* __restrict__ adj,
                                                 int* __restrict__ deg) {
  __shared__ __align__(16) ushort tA[64 * 128];
  __shared__ __align__(16) ushort tB[64 * 128];
  __shared__ u64 rowbits[64];
  const int tid = threadIdx.x;
  const int bid = blockIdx.x;
  int I0 = (bid & 63) * 64, J0 = (bid >> 6) * 64;
  if (tid < 64) rowbits[tid] = 0ull;
  for (int f = tid; f < 1024; f += 256) {
    int r = f >> 4, c = f & 15;
    int scnk = c ^ (r & 7);
    *(i32x4*)&tA[r * 128 + scnk * 8] = *(const i32x4*)(nfb + (size_t)(I0 + r) * NC + c * 8);
    *(i32x4*)&tB[r * 128 + scnk * 8] = *(const i32x4*)(nfb + (size_t)(J0 + r) * NC + c * 8);
  }
  __syncthreads();
  int w = tid >> 6, l = tid & 63;
  int r = l & 15, kg = l >> 4;
  f32x4 acc[4] = {{0.f, 0.f, 0.f, 0.f}, {0.f, 0.f, 0.f, 0.f},
                  {0.f, 0.f, 0.f, 0.f}, {0.f, 0.f, 0.f, 0.f}};
  int Ar = 16 * w + r;
  #pragma unroll
  for (int kk = 0; kk < 4; ++kk) {
    int chunkA = (kk * 4 + kg) ^ (Ar & 7);
    bf16x8 a = *(bf16x8*)&tA[Ar * 128 + chunkA * 8];
    #pragma unroll
    for (int j = 0; j < 4; ++j) {
      int Bc = 16 * j + r;
      int chunkB = (kk * 4 + kg) ^ (Bc & 7);
      bf16x8 bf = *(bf16x8*)&tB[Bc * 128 + chunkB * 8];
      acc[j] = __builtin_amdgcn_mfma_f32_16x16x32_bf16(a, bf, acc[j], 0, 0, 0);
    }
  }
  #pragma unroll
  for (int q = 0; q < 4; ++q) {
    u64 m = 0ull;
    #pragma unroll
    for (int j = 0; j < 4; ++j) {
      float simv = acc[j][q];
      if ((1.0f - simv) * 0.5f < 0.2f) m |= 1ull << (16 * j + (l & 15));
    }
    if (m) atomicOr(&rowbits[16 * w + (l >> 4) * 4 + q], m);
  }
  __syncthreads();
  if (tid < 64) {
    u64 rb = rowbits[tid];
    adj[(size_t)(I0 + tid) * 64 + (bid >> 6)] = rb;
    atomicAdd(&deg[I0 + tid], __popcll(rb));   // int sum, deterministic
  }
}

// ==================== K4: agg (deg-based) + GEMM(+bias) + scatter ====================
__global__ __launch_bounds__(256) void k4_kernel(const u64* __restrict__ adj,
                                                 const float* __restrict__ feats,
                                                 const int* __restrict__ deg,
                                                 const float* __restrict__ Wg,
                                                 const float* __restrict__ bg,
                                                 const int* __restrict__ sel,
                                                 float* __restrict__ out) {
  __shared__ __align__(16) float Wt[NC * 132];    // W transposed [cp][c]
  __shared__ __align__(16) float aggT[16 * 132];
  int tid = threadIdx.x;
  int r0 = blockIdx.x * 16;
  for (int f = tid; f < NC * NC; f += 256) {
    int c = f >> 7, cp = f & 127;
    Wt[cp * 132 + c] = Wg[f];
  }
  int w = tid >> 6, lane = tid & 63;
  for (int rr = 0; rr < 4; ++rr) {
    int lrow = w * 4 + rr;
    int row = r0 + lrow;
    u64 mw = adj[(size_t)row * 64 + lane];
    float dinv_i = 1.0f / sqrtf(fmaxf((float)deg[row], 1.0f));
    float acc0 = 0.f, acc1 = 0.f;
    for (int wi = 0; wi < 64; ++wi) {
      u64 w64 = __shfl((long long)mw, wi);
      while (w64) {
        int bit = __builtin_ctzll(w64);
        w64 &= w64 - 1;
        int j = wi * 64 + bit;            // ascending j (deterministic order)
        float dj = 1.0f / sqrtf(fmaxf((float)deg[j], 1.0f));
        acc0 += dj * feats[(size_t)j * NC + lane];
        acc1 += dj * feats[(size_t)j * NC + lane + 64];
      }
    }
    aggT[lrow * 132 + lane] = dinv_i * acc0;
    aggT[lrow * 132 + lane + 64] = dinv_i * acc1;
  }
  __syncthreads();
  int cp = tid & 127;
  int rsub = tid >> 7;
  float acc[8];
  float bb = bg[cp];
  #pragma unroll
  for (int q = 0; q < 8; ++q) acc[q] = bb;
  for (int c4 = 0; c4 < 32; ++c4) {
    float4 w4 = *(const float4*)&Wt[cp * 132 + c4 * 4];
    #pragma unroll
    for (int q = 0; q < 8; ++q) {
      float4 a4 = *(const float4*)&aggT[(rsub + 2 * q) * 132 + c4 * 4];
      acc[q] += a4.x * w4.x + a4.y * w4.y + a4.z * w4.z + a4.w * w4.w;
    }
  }
  #pragma unroll
  for (int q = 0; q < 8; ++q) {
    int row = r0 + rsub + 2 * q;
    int batch = row >> 8;
    int idx = sel[row];
    out[(size_t)(batch * NC + cp) * HWs + idx] = acc[q];
  }
}

extern "C" void kernel_launch(void* const* d_in, const int* in_sizes, int n_in,
                              void* d_out, int out_size, void* d_ws, size_t ws_size,
                              hipStream_t stream) {
  const float* z     = (const float*)d_in[0];
  const float* score = (const float*)d_in[1];
  const float* Wg    = (const float*)d_in[2];
  const float* bg    = (const float*)d_in[3];
  float* out = (float*)d_out;

  char* ws = (char*)d_ws;
  size_t off = 0;
  auto alloc = [&](size_t bytes) {
    void* p = ws + off;
    off = (off + bytes + 255) & ~(size_t)255;
    return p;
  };
  int* sel     = (int*)alloc(NN * sizeof(int));
  float* feats = (float*)alloc((size_t)NN * NC * sizeof(float));
  ushort* nfb  = (ushort*)alloc((size_t)NN * NC * sizeof(ushort));
  u64* adj     = (u64*)alloc((size_t)NN * 64 * sizeof(u64));
  int* deg     = (int*)alloc(NN * sizeof(int));

  k1_kernel<<<NB + K1_CPB, 256, 0, stream>>>(z, score, out, sel);
  k2_kernel<<<NN / 4, 256, 0, stream>>>(z, sel, feats, nfb, deg);
  k3_kernel<<<4096, 256, 0, stream>>>(nfb, adj, deg);
  k4_kernel<<<256, 256, 0, stream>>>(adj, feats, deg, Wg, bg, sel, out);
}